// Round 3
// baseline (231.504 us; speedup 1.0000x reference)
//
#include <hip/hip_runtime.h>

typedef float f32x4 __attribute__((ext_vector_type(4)));
typedef __bf16 bf16x8 __attribute__((ext_vector_type(8)));
typedef unsigned short u16x8 __attribute__((ext_vector_type(8)));

static constexpr int B_ = 8, Cin = 128, Cout = 128, K2 = 9;
static constexpr int HW  = 64 * 64;      // 4096
static constexpr int CHW = Cin * HW;     // 524288
static constexpr int KC  = Cin * K2;     // 1152

static __device__ __forceinline__ unsigned short f2bf(float f) {
  unsigned int u = __builtin_bit_cast(unsigned int, f);
  u = u + 0x7fffu + ((u >> 16) & 1u);
  return (unsigned short)(u >> 16);
}

// ---------------- prep: weight reorder / bf16 convert ----------------
__global__ __launch_bounds__(256) void prep_kernel(
    const float* __restrict__ dw, const float* __restrict__ ow,
    unsigned short* __restrict__ wsW, float* __restrict__ wsOffW) {
  int i = blockIdx.x * 256 + threadIdx.x;
  if (i < Cout * KC) {
    int oc = i / KC; int rem = i - oc * KC;
    int k = rem >> 7; int c = rem & 127;           // kc = k*128 + c
    wsW[i] = f2bf(dw[(oc * Cin + c) * K2 + k]);
  }
  if (i < Cin * K2) {                              // i = c*9 + r
#pragma unroll
    for (int oc = 0; oc < 18; ++oc)
      wsOffW[i * 20 + oc] = ow[oc * (Cin * K2) + i];
  }
}

// ---------------- offset conv + bilinear record precompute ----------------
__global__ __launch_bounds__(256) void offs_kernel(
    const float* __restrict__ x, const float* __restrict__ wsOffW,
    const float* __restrict__ ob, float4* __restrict__ w4out,
    unsigned int* __restrict__ idxout) {
  int bid = blockIdx.x;
  int b = bid >> 6, ho = bid & 63;
  int t = threadIdx.x;
  int wo = t & 63, grp = t >> 6;

  float acc[18];
#pragma unroll
  for (int i = 0; i < 18; ++i) acc[i] = 0.f;

  const float* xb = x + b * CHW;
  for (int ci = 0; ci < 32; ++ci) {
    int c = grp * 32 + ci;
    const float* bc = xb + c * HW;
    const float* wp = wsOffW + c * 180;            // 9*20 floats per c
#pragma unroll
    for (int r = 0; r < 9; ++r) {
      int ky = r / 3, kx = r % 3;
      int yv = ho + ky - 1, xc = wo + kx - 1;
      bool okl = ((unsigned)yv < 64u) && ((unsigned)xc < 64u);
      float xv = okl ? bc[yv * 64 + xc] : 0.f;
#pragma unroll
      for (int oc = 0; oc < 18; ++oc)
        acc[oc] += xv * wp[r * 20 + oc];
    }
  }

  __shared__ float red[4 * 18 * 64];
#pragma unroll
  for (int oc = 0; oc < 18; ++oc)
    red[(grp * 18 + oc) * 64 + wo] = acc[oc];
  __syncthreads();

  if (t < 64) {
    float o[18];
#pragma unroll
    for (int oc = 0; oc < 18; ++oc) {
      float s = ob[oc];
#pragma unroll
      for (int g = 0; g < 4; ++g) s += red[(g * 18 + oc) * 64 + t];
      o[oc] = s;
    }
#pragma unroll
    for (int k = 0; k < 9; ++k) {
      float dy = o[2 * k], dx = o[2 * k + 1];
      float py = (float)(ho - 1 + k / 3) + dy;
      float px = (float)(t - 1 + k % 3) + dx;
      float y0f = floorf(py), x0f = floorf(px);
      float wy1 = py - y0f, wy0 = 1.f - wy1;
      float wx1 = px - x0f, wx0 = 1.f - wx1;
      int y0 = (int)y0f, x0 = (int)x0f;
      bool vy0 = (unsigned)y0 < 64u, vy1 = (unsigned)(y0 + 1) < 64u;
      bool vx0 = (unsigned)x0 < 64u, vx1 = (unsigned)(x0 + 1) < 64u;
      float w00 = (vy0 && vx0) ? wy0 * wx0 : 0.f;
      float w01 = (vy0 && vx1) ? wy0 * wx1 : 0.f;
      float w10 = (vy1 && vx0) ? wy1 * wx0 : 0.f;
      float w11 = (vy1 && vx1) ? wy1 * wx1 : 0.f;
      int y0c = min(max(y0, 0), 63), y1c = min(max(y0 + 1, 0), 63);
      int xb2 = min(max(x0, 0), 62);
      unsigned off0 = (unsigned)(y0c * 64 + xb2);
      unsigned off1 = (unsigned)(y1c * 64 + xb2);
      unsigned pkw = off0 | (off1 << 12);
      if (x0 == 63) pkw |= (1u << 24);   // left value is loaded[1]
      if (x0 == -1) pkw |= (1u << 25);   // right value is loaded[0]
      int rec = (b * 9 + k) * HW + ho * 64 + t;
      w4out[rec] = make_float4(w00, w01, w10, w11);
      idxout[rec] = pkw;
    }
  }
}

// ---------------- fused deformable-im2col + MFMA GEMM + BN + SiLU ----------------
__global__ __launch_bounds__(256) void gemm_kernel(
    const float* __restrict__ x, const unsigned short* __restrict__ wsW,
    const float4* __restrict__ w4in, const unsigned int* __restrict__ idxin,
    const float* __restrict__ dbias, const float* __restrict__ gamma,
    const float* __restrict__ beta, const float* __restrict__ mean,
    const float* __restrict__ var, float* __restrict__ out) {
  int bid = blockIdx.x;
  int b = bid >> 6, ho = bid & 63;
  int t = threadIdx.x;
  int wo = t & 63, kgrp = t >> 6;
  int lane = t & 63, wv = t >> 6;
  int col = lane & 15, g = lane >> 4;

  __shared__ unsigned short S[64 * 40];  // [pos][kc_local], stride 40 (80B) pads banks

  f32x4 acc[2][4];
#pragma unroll
  for (int i = 0; i < 2; ++i)
#pragma unroll
    for (int j = 0; j < 4; ++j)
      acc[i][j] = (f32x4){0.f, 0.f, 0.f, 0.f};

  const float* xb = x + b * CHW;

  for (int k = 0; k < 9; ++k) {
    int rec = (b * 9 + k) * HW + ho * 64 + wo;
    float4 w4 = w4in[rec];
    unsigned pkw = idxin[rec];
    int off0 = pkw & 4095, off1 = (pkw >> 12) & 4095;
    bool s0 = (pkw >> 24) & 1, s1 = (pkw >> 25) & 1;

    for (int cc = 0; cc < 4; ++cc) {
      // gather 8 samples: c = cc*32 + kgrp*8 + j, pos = wo
      const float* p = xb + (cc * 32 + kgrp * 8) * HW;
      u16x8 smp;
#pragma unroll
      for (int j = 0; j < 8; ++j) {
        const float* q = p + j * HW;
        float v00 = q[off0], v01 = q[off0 + 1];
        float v10 = q[off1], v11 = q[off1 + 1];
        float gl0 = s0 ? v01 : v00, gr0 = s1 ? v00 : v01;
        float gl1 = s0 ? v11 : v10, gr1 = s1 ? v10 : v11;
        float sv = w4.x * gl0 + w4.y * gr0 + w4.z * gl1 + w4.w * gr1;
        smp[j] = f2bf(sv);
      }
      __syncthreads();   // previous chunk's B-frag reads complete
      *((u16x8*)&S[wo * 40 + kgrp * 8]) = smp;
      __syncthreads();   // S tile visible

      int kc0 = k * 128 + cc * 32;
      bf16x8 afr[2], bfr[4];
#pragma unroll
      for (int ot = 0; ot < 2; ++ot) {
        int row = wv * 32 + ot * 16 + col;
        afr[ot] = __builtin_bit_cast(
            bf16x8, *((const u16x8*)(wsW + row * KC + kc0 + g * 8)));
      }
#pragma unroll
      for (int pt = 0; pt < 4; ++pt)
        bfr[pt] = __builtin_bit_cast(
            bf16x8, *((const u16x8*)&S[(pt * 16 + col) * 40 + g * 8]));
#pragma unroll
      for (int ot = 0; ot < 2; ++ot)
#pragma unroll
        for (int pt = 0; pt < 4; ++pt)
          acc[ot][pt] = __builtin_amdgcn_mfma_f32_16x16x32_bf16(
              afr[ot], bfr[pt], acc[ot][pt], 0, 0, 0);
    }
  }

  // epilogue: bias + BN + SiLU, write NCHW
  float* op = out + b * (Cout * HW) + ho * 64;
#pragma unroll
  for (int ot = 0; ot < 2; ++ot) {
    int ocb = wv * 32 + ot * 16 + g * 4;
#pragma unroll
    for (int r = 0; r < 4; ++r) {
      int oc = ocb + r;
      float sc = gamma[oc] * rsqrtf(var[oc] + 1e-5f);
      float bs = beta[oc] - mean[oc] * sc;
      float db = dbias[oc];
#pragma unroll
      for (int pt = 0; pt < 4; ++pt) {
        float v = (acc[ot][pt][r] + db) * sc + bs;
        float o = v / (1.f + __expf(-v));
        op[oc * HW + pt * 16 + col] = o;
      }
    }
  }
}

extern "C" void kernel_launch(void* const* d_in, const int* in_sizes, int n_in,
                              void* d_out, int out_size, void* d_ws, size_t ws_size,
                              hipStream_t stream) {
  const float* x     = (const float*)d_in[0];
  const float* ow    = (const float*)d_in[1];
  const float* ob    = (const float*)d_in[2];
  const float* dw    = (const float*)d_in[3];
  const float* db    = (const float*)d_in[4];
  const float* gamma = (const float*)d_in[5];
  const float* beta  = (const float*)d_in[6];
  const float* mean  = (const float*)d_in[7];
  const float* var   = (const float*)d_in[8];

  char* wsc = (char*)d_ws;
  unsigned short* wsW = (unsigned short*)wsc;                // 294912 B
  float* wsOffW       = (float*)(wsc + 294912);              // 92160 B
  float4* w4rec       = (float4*)(wsc + 387072);             // 4718592 B (16B aligned)
  unsigned int* idxrec = (unsigned int*)(wsc + 5105664);     // 1179648 B

  prep_kernel<<<576, 256, 0, stream>>>(dw, ow, wsW, wsOffW);
  offs_kernel<<<512, 256, 0, stream>>>(x, wsOffW, ob, w4rec, idxrec);
  gemm_kernel<<<512, 256, 0, stream>>>(x, wsW, w4rec, idxrec, db, gamma, beta,
                                       mean, var, (float*)d_out);
}

// Round 5
// 195.147 us; speedup vs baseline: 1.1863x; 1.1863x over previous
//
#include <hip/hip_runtime.h>

typedef float f32x4 __attribute__((ext_vector_type(4)));
typedef __bf16 bf16x8 __attribute__((ext_vector_type(8)));
typedef unsigned short u16x8 __attribute__((ext_vector_type(8)));
typedef unsigned short u16x4 __attribute__((ext_vector_type(4)));

static constexpr int B_ = 8, Cin = 128, Cout = 128, K2 = 9;
static constexpr int HW  = 64 * 64;      // 4096
static constexpr int CHW = Cin * HW;     // 524288
static constexpr int KC  = Cin * K2;     // 1152

static __device__ __forceinline__ unsigned short f2bf(float f) {
  unsigned int u = __builtin_bit_cast(unsigned int, f);
  u = u + 0x7fffu + ((u >> 16) & 1u);
  return (unsigned short)(u >> 16);
}

// ---------------- prep: weight reorder / bf16 convert ----------------
__global__ __launch_bounds__(256) void prep_kernel(
    const float* __restrict__ dw, const float* __restrict__ ow,
    unsigned short* __restrict__ wsW, float* __restrict__ wsOffW) {
  int i = blockIdx.x * 256 + threadIdx.x;
  if (i < Cout * KC) {
    int oc = i / KC; int rem = i - oc * KC;
    int k = rem >> 7; int c = rem & 127;           // kc = k*128 + c
    wsW[i] = f2bf(dw[(oc * Cin + c) * K2 + k]);
  }
  if (i < Cin * K2) {                              // i = c*9 + r
#pragma unroll
    for (int oc = 0; oc < 18; ++oc)
      wsOffW[i * 20 + oc] = ow[oc * (Cin * K2) + i];
  }
}

// ---------------- offset conv + bilinear record precompute ----------------
__global__ __launch_bounds__(256) void offs_kernel(
    const float* __restrict__ x, const float* __restrict__ wsOffW,
    const float* __restrict__ ob, float4* __restrict__ w4out,
    unsigned int* __restrict__ idxout) {
  int bid = blockIdx.x;
  int swz = (bid & 7) * 64 + (bid >> 3);           // XCD swizzle, 512 blocks
  int b = swz >> 6, ho = swz & 63;
  int t = threadIdx.x;
  int wo = t & 63, grp = t >> 6;

  float acc[18];
#pragma unroll
  for (int i = 0; i < 18; ++i) acc[i] = 0.f;

  const float* xb = x + b * CHW;
  for (int ci = 0; ci < 32; ++ci) {
    int c = grp * 32 + ci;
    const float* bc = xb + c * HW;
    const float* wp = wsOffW + c * 180;            // 9*20 floats per c
#pragma unroll
    for (int r = 0; r < 9; ++r) {
      int ky = r / 3, kx = r % 3;
      int yv = ho + ky - 1, xc = wo + kx - 1;
      bool okl = ((unsigned)yv < 64u) && ((unsigned)xc < 64u);
      float xv = okl ? bc[yv * 64 + xc] : 0.f;
#pragma unroll
      for (int oc = 0; oc < 18; ++oc)
        acc[oc] += xv * wp[r * 20 + oc];
    }
  }

  __shared__ float red[4 * 18 * 64];
#pragma unroll
  for (int oc = 0; oc < 18; ++oc)
    red[(grp * 18 + oc) * 64 + wo] = acc[oc];
  __syncthreads();

  if (t < 64) {
    float o[18];
#pragma unroll
    for (int oc = 0; oc < 18; ++oc) {
      float s = ob[oc];
#pragma unroll
      for (int g = 0; g < 4; ++g) s += red[(g * 18 + oc) * 64 + t];
      o[oc] = s;
    }
#pragma unroll
    for (int k = 0; k < 9; ++k) {
      float dy = o[2 * k], dx = o[2 * k + 1];
      float py = (float)(ho - 1 + k / 3) + dy;
      float px = (float)(t - 1 + k % 3) + dx;
      float y0f = floorf(py), x0f = floorf(px);
      float wy1 = py - y0f, wy0 = 1.f - wy1;
      float wx1 = px - x0f, wx0 = 1.f - wx1;
      int y0 = (int)y0f, x0 = (int)x0f;
      bool vy0 = (unsigned)y0 < 64u, vy1 = (unsigned)(y0 + 1) < 64u;
      bool vx0 = (unsigned)x0 < 64u, vx1 = (unsigned)(x0 + 1) < 64u;
      float w00 = (vy0 && vx0) ? wy0 * wx0 : 0.f;
      float w01 = (vy0 && vx1) ? wy0 * wx1 : 0.f;
      float w10 = (vy1 && vx0) ? wy1 * wx0 : 0.f;
      float w11 = (vy1 && vx1) ? wy1 * wx1 : 0.f;
      int y0c = min(max(y0, 0), 63), y1c = min(max(y0 + 1, 0), 63);
      int xb2 = min(max(x0, 0), 62);
      unsigned off0 = (unsigned)(y0c * 64 + xb2);
      unsigned off1 = (unsigned)(y1c * 64 + xb2);
      unsigned pkw = off0 | (off1 << 12);
      if (x0 == 63) pkw |= (1u << 24);   // left value is loaded[1]
      if (x0 == -1) pkw |= (1u << 25);   // right value is loaded[0]
      int rec = (b * 9 + k) * HW + ho * 64 + t;
      w4out[rec] = make_float4(w00, w01, w10, w11);
      idxout[rec] = pkw;
    }
  }
}

// ---------------- fused deformable-im2col + MFMA GEMM + BN + SiLU ----------------
// 512 threads = 8 waves; wave w owns oc [w*16, w*16+16), all 64 pos.
// Double-buffered S, ONE __syncthreads per 32-channel chunk. Gather loads for
// chunk n+1 are issued after sync(n) and consumed before sync(n+1), so the
// vmcnt(0) drain in __syncthreads costs ~nothing; A-frag is loaded and consumed
// within the same body (no barrier crossing).
__global__ __launch_bounds__(512, 4) void gemm_kernel(
    const float* __restrict__ x, const unsigned short* __restrict__ wsW,
    const float4* __restrict__ w4in, const unsigned int* __restrict__ idxin,
    const float* __restrict__ dbias, const float* __restrict__ gamma,
    const float* __restrict__ beta, const float* __restrict__ mean,
    const float* __restrict__ var, float* __restrict__ out) {
  int bid = blockIdx.x;
  int swz = (bid & 7) * 64 + (bid >> 3);           // XCD i <- batch i
  int b = swz >> 6, ho = swz & 63;
  int t = threadIdx.x;
  int wo = t & 63, kgrp = t >> 6;                  // gather role: 8 grp x 4 ch
  int lane = t & 63, w = t >> 6;                   // mfma role
  int col = lane & 15, g = lane >> 4;

  __shared__ unsigned short S[2][64 * 40];         // [pos][c_local], stride 40

  f32x4 acc[4];
#pragma unroll
  for (int j = 0; j < 4; ++j) acc[j] = (f32x4){0.f, 0.f, 0.f, 0.f};

  const float* xb = x + b * CHW;
  const unsigned short* wrow = wsW + (w * 16 + col) * KC + g * 8;
  const float4* w4p = w4in + b * 9 * HW + ho * 64 + wo;
  const unsigned int* idxp = idxin + b * 9 * HW + ho * 64 + wo;

  float4 cw4 = w4p[0];                             // rec[k=0]
  unsigned cpk = idxp[0];
  float4 nw4 = cw4;                                // rec[k+1], loaded in body 0
  unsigned npk = cpk;

  float CA[16], CB[16];

  { // prologue: gather chunk 0 with rec[0]
    int o0 = cpk & 4095, o1 = (cpk >> 12) & 4095;
    const float* p = xb + kgrp * 4 * HW;
#pragma unroll
    for (int j = 0; j < 4; ++j) {
      const float* q = p + j * HW;
      CA[4 * j + 0] = q[o0]; CA[4 * j + 1] = q[o0 + 1];
      CA[4 * j + 2] = q[o1]; CA[4 * j + 3] = q[o1 + 1];
    }
  }

  auto body = [&](int n, float (&CUR)[16], float (&NXT)[16]) {
    if ((n & 3) == 0 && n) { cw4 = nw4; cpk = npk; }   // rotate rec at k boundary
    // A-frag for chunk n: loaded here, consumed at this body's MFMA (L2-resident)
    u16x8 af = *(const u16x8*)(wrow + n * 32);
    bool cs0 = (cpk >> 24) & 1, cs1 = (cpk >> 25) & 1;
    u16x4 smp;
#pragma unroll
    for (int j = 0; j < 4; ++j) {
      float v00 = CUR[4 * j + 0], v01 = CUR[4 * j + 1];
      float v10 = CUR[4 * j + 2], v11 = CUR[4 * j + 3];
      float gl0 = cs0 ? v01 : v00, gr0 = cs1 ? v00 : v01;
      float gl1 = cs0 ? v11 : v10, gr1 = cs1 ? v10 : v11;
      smp[j] = f2bf(cw4.x * gl0 + cw4.y * gr0 + cw4.z * gl1 + cw4.w * gr1);
    }
    *(u16x4*)&S[n & 1][wo * 40 + kgrp * 4] = smp;
    __syncthreads();                               // full fence: write visible
    if (n < 35) {                                  // gather chunk n+1
      unsigned gpk = ((n & 3) == 3) ? npk : cpk;   // k+1's rec at cc==3
      int o0 = gpk & 4095, o1 = (gpk >> 12) & 4095;
      const float* p = xb + (((n + 1) & 3) * 32 + kgrp * 4) * HW;
#pragma unroll
      for (int j = 0; j < 4; ++j) {
        const float* q = p + j * HW;
        NXT[4 * j + 0] = q[o0]; NXT[4 * j + 1] = q[o0 + 1];
        NXT[4 * j + 2] = q[o1]; NXT[4 * j + 3] = q[o1 + 1];
      }
    }
    if ((n & 3) == 0 && n < 32) {                  // prefetch rec[k+1]
      nw4 = w4p[(n / 4 + 1) * HW];
      npk = idxp[(n / 4 + 1) * HW];
    }
#pragma unroll
    for (int pt = 0; pt < 4; ++pt) {
      bf16x8 bfr = *(const bf16x8*)&S[n & 1][(pt * 16 + col) * 40 + g * 8];
      acc[pt] = __builtin_amdgcn_mfma_f32_16x16x32_bf16(
          __builtin_bit_cast(bf16x8, af), bfr, acc[pt], 0, 0, 0);
    }
  };

  for (int nn = 0; nn < 36; nn += 2) {
    body(nn, CA, CB);
    body(nn + 1, CB, CA);
  }

  // epilogue: bias + BN + SiLU, write NCHW
  float* op = out + b * (Cout * HW) + ho * 64;
  int ocb = w * 16 + g * 4;
#pragma unroll
  for (int r = 0; r < 4; ++r) {
    int oc = ocb + r;
    float sc = gamma[oc] * rsqrtf(var[oc] + 1e-5f);
    float bs = beta[oc] - mean[oc] * sc;
    float db = dbias[oc];
#pragma unroll
    for (int pt = 0; pt < 4; ++pt) {
      float v = (acc[pt][r] + db) * sc + bs;
      op[oc * HW + pt * 16 + col] = v / (1.f + __expf(-v));
    }
  }
}

extern "C" void kernel_launch(void* const* d_in, const int* in_sizes, int n_in,
                              void* d_out, int out_size, void* d_ws, size_t ws_size,
                              hipStream_t stream) {
  const float* x     = (const float*)d_in[0];
  const float* ow    = (const float*)d_in[1];
  const float* ob    = (const float*)d_in[2];
  const float* dw    = (const float*)d_in[3];
  const float* db    = (const float*)d_in[4];
  const float* gamma = (const float*)d_in[5];
  const float* beta  = (const float*)d_in[6];
  const float* mean  = (const float*)d_in[7];
  const float* var   = (const float*)d_in[8];

  char* wsc = (char*)d_ws;
  unsigned short* wsW = (unsigned short*)wsc;                // 294912 B
  float* wsOffW       = (float*)(wsc + 294912);              // 92160 B
  float4* w4rec       = (float4*)(wsc + 387072);             // 4718592 B
  unsigned int* idxrec = (unsigned int*)(wsc + 5105664);     // 1179648 B

  prep_kernel<<<576, 256, 0, stream>>>(dw, ow, wsW, wsOffW);
  offs_kernel<<<512, 256, 0, stream>>>(x, wsOffW, ob, w4rec, idxrec);
  gemm_kernel<<<512, 512, 0, stream>>>(x, wsW, w4rec, idxrec, db, gamma, beta,
                                       mean, var, (float*)d_out);
}

// Round 6
// 135.728 us; speedup vs baseline: 1.7056x; 1.4378x over previous
//
#include <hip/hip_runtime.h>

typedef float f32x4 __attribute__((ext_vector_type(4)));
typedef __bf16 bf16x8 __attribute__((ext_vector_type(8)));
typedef unsigned short u16x8 __attribute__((ext_vector_type(8)));

static constexpr int B_ = 8, Cin = 128, Cout = 128, K2 = 9;
static constexpr int HW  = 64 * 64;      // 4096
static constexpr int CHW = Cin * HW;     // 524288
static constexpr int KC  = Cin * K2;     // 1152
static constexpr int SLD = 136;          // S row stride (u16), 272B = 17*16B

static __device__ __forceinline__ unsigned short f2bf(float f) {
  unsigned int u = __builtin_bit_cast(unsigned int, f);
  u = u + 0x7fffu + ((u >> 16) & 1u);
  return (unsigned short)(u >> 16);
}

// ---------------- prep: weight reorder / bf16 convert ----------------
__global__ __launch_bounds__(256) void prep_kernel(
    const float* __restrict__ dw, const float* __restrict__ ow,
    unsigned short* __restrict__ wsW, unsigned short* __restrict__ wOffB) {
  int i = blockIdx.x * 256 + threadIdx.x;
  if (i < Cout * KC) {                             // deform W: [oc][k*128+c]
    int oc = i / KC; int rem = i - oc * KC;
    int k = rem >> 7; int c = rem & 127;
    wsW[i] = f2bf(dw[(oc * Cin + c) * K2 + k]);
  }
  if (i < 32 * KC) {                               // offset W: [oc pad32][r*128+c]
    int oc = i / KC; int rem = i - oc * KC;
    int r = rem >> 7; int c = rem & 127;
    float v = (oc < 18) ? ow[(oc * Cin + c) * K2 + r] : 0.f;
    wOffB[i] = f2bf(v);
  }
}

// ---------------- offset conv (MFMA) + bilinear record precompute ----------------
// 256 thr = 4 waves. Tile: 32 oc (18 used) x 64 pos, K=1152 (r-major, c within).
// B-matrix = regular im2col of x (zero-padded edges), staged per r (128 ch).
__global__ __launch_bounds__(256) void offs_kernel(
    const float* __restrict__ x, const unsigned short* __restrict__ wOffB,
    const float* __restrict__ ob, float4* __restrict__ w4out,
    unsigned int* __restrict__ idxout) {
  int bid = blockIdx.x;
  int swz = (bid & 7) * 64 + (bid >> 3);           // XCD swizzle
  int b = swz >> 6, ho = swz & 63;
  int t = threadIdx.x;
  int pos = t & 63, cg = t >> 6;                   // staging: 4 cg x 32 ch
  int lane = t & 63, w = t >> 6;                   // mfma: wave w = pos-tile w
  int col = lane & 15, g = lane >> 4;

  __shared__ unsigned short So[2][64 * SLD];
  __shared__ float T[64 * 20];

  f32x4 acc[2];
  acc[0] = (f32x4){0.f, 0.f, 0.f, 0.f};
  acc[1] = (f32x4){0.f, 0.f, 0.f, 0.f};

  const float* xb = x + b * CHW;
  const unsigned short* a0 = wOffB + col * KC + g * 8;        // Mtile0 row
  const unsigned short* a1 = wOffB + (16 + col) * KC + g * 8; // Mtile1 row

  auto stage = [&](int r, int buf) {
    int ky = r / 3, kx = r % 3;
    int yv = ho + ky - 1, xc = pos + kx - 1;
    bool ok = ((unsigned)yv < 64u) && ((unsigned)xc < 64u);
    const float* q0 = xb + yv * 64 + xc + cg * 32 * HW;
#pragma unroll
    for (int i8 = 0; i8 < 4; ++i8) {
      u16x8 sm;
#pragma unroll
      for (int j = 0; j < 8; ++j) {
        float v = ok ? q0[(i8 * 8 + j) * HW] : 0.f;
        sm[j] = f2bf(v);
      }
      *(u16x8*)&So[buf][pos * SLD + cg * 32 + i8 * 8] = sm;
    }
  };

  stage(0, 0);
  __syncthreads();

  for (int r = 0; r < 9; ++r) {
    int cur = r & 1;
    if (r < 8) stage(r + 1, cur ^ 1);
#pragma unroll
    for (int ks = 0; ks < 4; ++ks) {
      bf16x8 bfr = *(const bf16x8*)&So[cur][(w * 16 + col) * SLD + ks * 32 + g * 8];
      u16x8 af0 = *(const u16x8*)(a0 + r * 128 + ks * 32);
      u16x8 af1 = *(const u16x8*)(a1 + r * 128 + ks * 32);
      acc[0] = __builtin_amdgcn_mfma_f32_16x16x32_bf16(
          __builtin_bit_cast(bf16x8, af0), bfr, acc[0], 0, 0, 0);
      acc[1] = __builtin_amdgcn_mfma_f32_16x16x32_bf16(
          __builtin_bit_cast(bf16x8, af1), bfr, acc[1], 0, 0, 0);
    }
    __syncthreads();
  }

  // transpose D -> T[pos][oc] with bias
#pragma unroll
  for (int m = 0; m < 2; ++m)
#pragma unroll
    for (int rg = 0; rg < 4; ++rg) {
      int row = m * 16 + g * 4 + rg;
      if (row < 18) T[(w * 16 + col) * 20 + row] = acc[m][rg] + ob[row];
    }
  __syncthreads();

  if (t < 64) {
#pragma unroll
    for (int k = 0; k < 9; ++k) {
      float dy = T[t * 20 + 2 * k], dx = T[t * 20 + 2 * k + 1];
      float py = (float)(ho - 1 + k / 3) + dy;
      float px = (float)(t - 1 + k % 3) + dx;
      float y0f = floorf(py), x0f = floorf(px);
      float wy1 = py - y0f, wy0 = 1.f - wy1;
      float wx1 = px - x0f, wx0 = 1.f - wx1;
      int y0 = (int)y0f, x0 = (int)x0f;
      bool vy0 = (unsigned)y0 < 64u, vy1 = (unsigned)(y0 + 1) < 64u;
      bool vx0 = (unsigned)x0 < 64u, vx1 = (unsigned)(x0 + 1) < 64u;
      float w00 = (vy0 && vx0) ? wy0 * wx0 : 0.f;
      float w01 = (vy0 && vx1) ? wy0 * wx1 : 0.f;
      float w10 = (vy1 && vx0) ? wy1 * wx0 : 0.f;
      float w11 = (vy1 && vx1) ? wy1 * wx1 : 0.f;
      int y0c = min(max(y0, 0), 63), y1c = min(max(y0 + 1, 0), 63);
      int xb2 = min(max(x0, 0), 62);
      unsigned off0 = (unsigned)(y0c * 64 + xb2);
      unsigned off1 = (unsigned)(y1c * 64 + xb2);
      unsigned pkw = off0 | (off1 << 12);
      if (x0 == 63) pkw |= (1u << 24);
      if (x0 == -1) pkw |= (1u << 25);
      int rec = (b * 9 + k) * HW + ho * 64 + t;
      w4out[rec] = make_float4(w00, w01, w10, w11);
      idxout[rec] = pkw;
    }
  }
}

// ---------------- fused deformable-im2col + MFMA GEMM + BN + SiLU ----------------
// 512 thr = 8 waves; wave w owns oc [w*16, w*16+16), all 64 pos.
// One barrier per k (9 total). Per thread per body: 64 independent gather loads
// (16 ch x 4 corners) in two 32-load halves interleaved with the 16 MFMA.
__global__ __launch_bounds__(512, 4) void gemm_kernel(
    const float* __restrict__ x, const unsigned short* __restrict__ wsW,
    const float4* __restrict__ w4in, const unsigned int* __restrict__ idxin,
    const float* __restrict__ dbias, const float* __restrict__ gamma,
    const float* __restrict__ beta, const float* __restrict__ mean,
    const float* __restrict__ var, float* __restrict__ out) {
  int bid = blockIdx.x;
  int swz = (bid & 7) * 64 + (bid >> 3);           // XCD i <- batch i
  int b = swz >> 6, ho = swz & 63;
  int t = threadIdx.x;
  int pos = t & 63, cg = t >> 6;                   // gather: 8 cg x 16 ch
  int lane = t & 63, w = t >> 6;
  int col = lane & 15, g = lane >> 4;

  __shared__ unsigned short S[2][64 * SLD];

  f32x4 acc[4];
#pragma unroll
  for (int j = 0; j < 4; ++j) acc[j] = (f32x4){0.f, 0.f, 0.f, 0.f};

  const float* xb = x + b * CHW;
  const unsigned short* wrow = wsW + (w * 16 + col) * KC + g * 8;
  const float4* w4p = w4in + b * 9 * HW + ho * 64 + pos;
  const unsigned int* idxp = idxin + b * 9 * HW + ho * 64 + pos;
  const float* qA = xb + cg * 16 * HW;             // gather ch base, half A
  const float* qB = xb + (cg * 16 + 8) * HW;       // half B

  // prologue: gather k=0, write S[0]
  {
    float4 gw4 = w4p[0];
    unsigned gpk = idxp[0];
    int o0 = gpk & 4095, o1 = (gpk >> 12) & 4095;
    bool s0 = (gpk >> 24) & 1, s1 = (gpk >> 25) & 1;
#pragma unroll
    for (int h = 0; h < 2; ++h) {
      const float* q = h ? qB : qA;
      u16x8 sm;
#pragma unroll
      for (int j = 0; j < 8; ++j) {
        const float* p = q + j * HW;
        float v00 = p[o0], v01 = p[o0 + 1], v10 = p[o1], v11 = p[o1 + 1];
        float gl0 = s0 ? v01 : v00, gr0 = s1 ? v00 : v01;
        float gl1 = s0 ? v11 : v10, gr1 = s1 ? v10 : v11;
        sm[j] = f2bf(gw4.x * gl0 + gw4.y * gr0 + gw4.z * gl1 + gw4.w * gr1);
      }
      *(u16x8*)&S[0][pos * SLD + cg * 16 + h * 8] = sm;
    }
  }
  float4 rw4n = w4p[HW];                           // rec[1]
  unsigned rpkn = idxp[HW];
  __syncthreads();

  for (int k = 0; k < 9; ++k) {
    int cur = k & 1;
    bool hasg = (k < 8);
    float4 gw4; int o0 = 0, o1 = 0; bool s0 = false, s1 = false;
    float RA[32], RB[32];
    if (hasg) {
      gw4 = rw4n;
      unsigned gpk = rpkn;
      o0 = gpk & 4095; o1 = (gpk >> 12) & 4095;
      s0 = (gpk >> 24) & 1; s1 = (gpk >> 25) & 1;
      if (k < 7) { rw4n = w4p[(k + 2) * HW]; rpkn = idxp[(k + 2) * HW]; }
    }
    // A-frags for this k (L2-hot)
    u16x8 af[4];
#pragma unroll
    for (int ks = 0; ks < 4; ++ks)
      af[ks] = *(const u16x8*)(wrow + k * 128 + ks * 32);
    if (hasg) {                                    // issue gather half A
#pragma unroll
      for (int j = 0; j < 8; ++j) {
        const float* p = qA + j * HW;
        RA[4 * j + 0] = p[o0]; RA[4 * j + 1] = p[o0 + 1];
        RA[4 * j + 2] = p[o1]; RA[4 * j + 3] = p[o1 + 1];
      }
    }
#pragma unroll
    for (int pt = 0; pt < 2; ++pt)                 // MFMA pt 0,1
#pragma unroll
      for (int ks = 0; ks < 4; ++ks) {
        bf16x8 bfr = *(const bf16x8*)&S[cur][(pt * 16 + col) * SLD + ks * 32 + g * 8];
        acc[pt] = __builtin_amdgcn_mfma_f32_16x16x32_bf16(
            __builtin_bit_cast(bf16x8, af[ks]), bfr, acc[pt], 0, 0, 0);
      }
    if (hasg) {                                    // issue half B, combine+write A
#pragma unroll
      for (int j = 0; j < 8; ++j) {
        const float* p = qB + j * HW;
        RB[4 * j + 0] = p[o0]; RB[4 * j + 1] = p[o1 + 1];  // placeholder order fixed below
        RB[4 * j + 1] = p[o0 + 1];
        RB[4 * j + 2] = p[o1]; RB[4 * j + 3] = p[o1 + 1];
      }
      u16x8 sm;
#pragma unroll
      for (int j = 0; j < 8; ++j) {
        float v00 = RA[4 * j], v01 = RA[4 * j + 1], v10 = RA[4 * j + 2], v11 = RA[4 * j + 3];
        float gl0 = s0 ? v01 : v00, gr0 = s1 ? v00 : v01;
        float gl1 = s0 ? v11 : v10, gr1 = s1 ? v10 : v11;
        sm[j] = f2bf(gw4.x * gl0 + gw4.y * gr0 + gw4.z * gl1 + gw4.w * gr1);
      }
      *(u16x8*)&S[cur ^ 1][pos * SLD + cg * 16] = sm;
    }
#pragma unroll
    for (int pt = 2; pt < 4; ++pt)                 // MFMA pt 2,3
#pragma unroll
      for (int ks = 0; ks < 4; ++ks) {
        bf16x8 bfr = *(const bf16x8*)&S[cur][(pt * 16 + col) * SLD + ks * 32 + g * 8];
        acc[pt] = __builtin_amdgcn_mfma_f32_16x16x32_bf16(
            __builtin_bit_cast(bf16x8, af[ks]), bfr, acc[pt], 0, 0, 0);
      }
    if (hasg) {                                    // combine+write half B
      u16x8 sm;
#pragma unroll
      for (int j = 0; j < 8; ++j) {
        float v00 = RB[4 * j], v01 = RB[4 * j + 1], v10 = RB[4 * j + 2], v11 = RB[4 * j + 3];
        float gl0 = s0 ? v01 : v00, gr0 = s1 ? v00 : v01;
        float gl1 = s0 ? v11 : v10, gr1 = s1 ? v10 : v11;
        sm[j] = f2bf(gw4.x * gl0 + gw4.y * gr0 + gw4.z * gl1 + gw4.w * gr1);
      }
      *(u16x8*)&S[cur ^ 1][pos * SLD + cg * 16 + 8] = sm;
    }
    __syncthreads();
  }

  // epilogue: bias + BN + SiLU, write NCHW
  float* op = out + b * (Cout * HW) + ho * 64;
  int ocb = w * 16 + g * 4;
#pragma unroll
  for (int r = 0; r < 4; ++r) {
    int oc = ocb + r;
    float sc = gamma[oc] * rsqrtf(var[oc] + 1e-5f);
    float bs = beta[oc] - mean[oc] * sc;
    float db = dbias[oc];
#pragma unroll
    for (int pt = 0; pt < 4; ++pt) {
      float v = (acc[pt][r] + db) * sc + bs;
      op[oc * HW + pt * 16 + col] = v / (1.f + __expf(-v));
    }
  }
}

extern "C" void kernel_launch(void* const* d_in, const int* in_sizes, int n_in,
                              void* d_out, int out_size, void* d_ws, size_t ws_size,
                              hipStream_t stream) {
  const float* x     = (const float*)d_in[0];
  const float* ow    = (const float*)d_in[1];
  const float* ob    = (const float*)d_in[2];
  const float* dw    = (const float*)d_in[3];
  const float* db    = (const float*)d_in[4];
  const float* gamma = (const float*)d_in[5];
  const float* beta  = (const float*)d_in[6];
  const float* mean  = (const float*)d_in[7];
  const float* var   = (const float*)d_in[8];

  char* wsc = (char*)d_ws;
  unsigned short* wsW   = (unsigned short*)wsc;              // 294912 B
  unsigned short* wOffB = (unsigned short*)(wsc + 294912);   // 73728 B
  float4* w4rec         = (float4*)(wsc + 368640);           // 4718592 B
  unsigned int* idxrec  = (unsigned int*)(wsc + 5087232);    // 1179648 B

  prep_kernel<<<576, 256, 0, stream>>>(dw, ow, wsW, wOffB);
  offs_kernel<<<512, 256, 0, stream>>>(x, wOffB, ob, w4rec, idxrec);
  gemm_kernel<<<512, 512, 0, stream>>>(x, wsW, w4rec, idxrec, db, gamma, beta,
                                       mean, var, (float*)d_out);
}